// Round 12
// baseline (273.382 us; speedup 1.0000x reference)
//
#include <hip/hip_runtime.h>
#include <cstdint>

#define BATCH 8
#define NPART 2048
#define DDIM 8
#define NN (NPART * NPART) /* 4194304 ordered pairs per batch */

#define MJCHUNK 128   // median j-tile: 4.6 KB stage + 32 KB hist -> 4 blocks/CU

constexpr float LR = 0.1f;
constexpr float ALPHA = 0.9f;
constexpr float EPS = 1e-8f;
constexpr float INV_N = 1.0f / (float)NPART;
constexpr float LOG2E = 1.44269504088896340736f;

typedef float v2f __attribute__((ext_vector_type(2)));
typedef float v4f __attribute__((ext_vector_type(4)));
typedef __attribute__((ext_vector_type(8))) short bf16x8;
typedef __attribute__((ext_vector_type(16))) float f32x16;

union FragU { bf16x8 v; unsigned u[4]; };

// pack two floats to bf16 (truncation) into one u32: f0 -> low16, f1 -> high16.
// Truncation is fine: the lo-frag compensates the residual exactly.
__device__ __forceinline__ unsigned pk_bf16(float f0, float f1) {
    return (__float_as_uint(f0) >> 16) | (__float_as_uint(f1) & 0xFFFF0000u);
}
__device__ __forceinline__ float btrunc(float f) {
    return __uint_as_float(__float_as_uint(f) & 0xFFFF0000u);
}

// ---------------------------------------------------------------------------
// init: zero radix histograms + select state (RMSprop s is never pre-zeroed:
// the first svgd step computes s = (1-a)*phi^2 directly, not reading s).
// ---------------------------------------------------------------------------
__global__ __launch_bounds__(256) void init_ws_k(unsigned* __restrict__ hist,
                                                 unsigned* __restrict__ prefix,
                                                 unsigned* __restrict__ rank) {
    const int tid = blockIdx.x * 256 + threadIdx.x;
    if (tid < BATCH * 2 * 256) hist[tid] = 0u;
    if (tid < BATCH * 2) {
        prefix[tid] = 0u;
        rank[tid] = (unsigned)(NN / 2) + (unsigned)(tid & 1); // 2097152 / 2097153
    }
}

// ---------------------------------------------------------------------------
// SYMMETRIC radix-select histogram pass (round-11 proven, unchanged).
// ---------------------------------------------------------------------------
__global__ __launch_bounds__(256) void median_hist_k(const float* __restrict__ x,
                                                     unsigned* __restrict__ hist,
                                                     const unsigned* __restrict__ prefix,
                                                     int shift) {
    __shared__ __align__(16) v4f xs0[MJCHUNK]; // xj dims 0-3
    __shared__ __align__(16) v4f xs1[MJCHUNK]; // xj dims 4-7
    __shared__ float rs[MJCHUNK];              // |xj|^2
    __shared__ unsigned lh[256 * 32];          // 32 KB slot-privatized bins

    const int b = blockIdx.x;
    const int tid = threadIdx.x;
    const int lane = tid & 63;   // j-lane
    const int slot = tid & 31;
    const int trow = tid >> 6;   // 0..3
    const float* xb = x + (size_t)b * NPART * DDIM;

    const unsigned p0 = prefix[2 * b + 0];
    const unsigned p1 = prefix[2 * b + 1];
    const bool same = (p0 == p1);
    const unsigned mask = (shift == 24) ? 0u : (0xFFFFFFFFu << (shift + 8));

    const int nsel = same ? 1 : 2;
    for (int sel = 0; sel < nsel; ++sel) {
        const unsigned pref = sel ? p1 : p0;
        __syncthreads();
        for (int t = tid; t < 256 * 32; t += 256) lh[t] = 0u;

        for (int sp = 0; sp < 2; ++sp) {
            const int strip = sp ? (255 - (int)blockIdx.y) : (int)blockIdx.y;
            const int ibase = strip * 8 + trow * 2;
            v2f xi[2][4];
            float q[2];
#pragma unroll
            for (int rr = 0; rr < 2; ++rr) {
                const v4f t0 = ((const v4f*)(xb + (size_t)(ibase + rr) * DDIM))[0];
                const v4f t1 = ((const v4f*)(xb + (size_t)(ibase + rr) * DDIM))[1];
                xi[rr][0] = t0.xy; xi[rr][1] = t0.zw;
                xi[rr][2] = t1.xy; xi[rr][3] = t1.zw;
                q[rr] = t0.x * t0.x + t0.y * t0.y + t0.z * t0.z + t0.w * t0.w
                      + t1.x * t1.x + t1.y * t1.y + t1.z * t1.z + t1.w * t1.w;
            }
            const int c0 = (strip >> 4) * MJCHUNK; // first chunk touching strip
            for (int cbase = c0; cbase < NPART; cbase += MJCHUNK) {
                __syncthreads();
                for (int t = tid; t < MJCHUNK; t += 256) {
                    const v4f u0 = ((const v4f*)(xb + (size_t)(cbase + t) * DDIM))[0];
                    const v4f u1 = ((const v4f*)(xb + (size_t)(cbase + t) * DDIM))[1];
                    xs0[t] = u0;
                    xs1[t] = u1;
                    rs[t] = u0.x * u0.x + u0.y * u0.y + u0.z * u0.z + u0.w * u0.w
                          + u1.x * u1.x + u1.y * u1.y + u1.z * u1.z + u1.w * u1.w;
                }
                __syncthreads();
#pragma unroll
                for (int j = lane; j < MJCHUNK; j += 64) {
                    const int jg = cbase + j;
                    const v4f A = xs0[j];
                    const v4f B = xs1[j];
                    const float r = rs[j];
                    const v2f A0 = A.xy, A1 = A.zw, B0 = B.xy, B1 = B.zw;
#pragma unroll
                    for (int rr = 0; rr < 2; ++rr) {
                        v2f p = A0 * xi[rr][0];
                        p += A1 * xi[rr][1];
                        p += B0 * xi[rr][2];
                        p += B1 * xi[rr][3];
                        const float sq = fmaxf(fmaf(-2.0f, p.x + p.y, q[rr] + r), 0.0f);
                        const unsigned u = __float_as_uint(sq);
                        if (jg > ibase + rr && (u & mask) == pref)
                            atomicAdd(&lh[((u >> shift) & 255u) * 32 + slot], 2u);
                    }
                }
            }
        }
        __syncthreads();
        unsigned tot = 0;
#pragma unroll
        for (int sct = 0; sct < 32; ++sct) tot += lh[tid * 32 + ((sct + tid) & 31)];
        if (tot) {
            atomicAdd(&hist[b * 512 + sel * 256 + tid], tot);
            if (same) atomicAdd(&hist[b * 512 + 256 + tid], tot);
        }
    }
}

// ---------------------------------------------------------------------------
// scan (round-11 proven, unchanged): diagonal zeros added analytically.
// Final round (shift==8): hpar = { -log2e/h, 2/h }.
// ---------------------------------------------------------------------------
__global__ void median_scan_k(unsigned* __restrict__ hist,
                              unsigned* __restrict__ prefix,
                              unsigned* __restrict__ rank,
                              int shift,
                              float* __restrict__ hpar) {
    __shared__ unsigned selv[16];
    const int t = threadIdx.x;
    if (t < 16) {
        const unsigned r = rank[t];
        const unsigned pref = prefix[t];
        const unsigned* hb = hist + t * 256;
        unsigned cum = 0;
        int bin = 0;
        for (; bin < 256; ++bin) {
            unsigned c = hb[bin];
            if (bin == 0 && pref == 0u) c += (unsigned)NPART; // diagonal zeros
            if (cum + c >= r) break;
            cum += c;
        }
        if (bin > 255) bin = 255;
        const unsigned np = pref | ((unsigned)bin << shift);
        prefix[t] = np;
        rank[t] = r - cum;
        selv[t] = np;
    }
    __syncthreads();
    for (int q = t; q < 16 * 256; q += 64) hist[q] = 0u;
    if (shift == 8 && t < BATCH) {
        const float v1 = __uint_as_float(selv[2 * t + 0]);
        const float v2 = __uint_as_float(selv[2 * t + 1]);
        const float med = 0.5f * (sqrtf(v1) + sqrtf(v2));
        const float h = (med * med) / logf((float)NPART);
        hpar[2 * t + 0] = -LOG2E / h;
        hpar[2 * t + 1] = 2.0f / h;
    }
}

// ---------------------------------------------------------------------------
// MFMA SVGD step. Distance matrix via homogeneous-coordinate matmul:
//   sq(j,i) = [xj(8), qj, 1] . [-2xi(8), 1, qi]   (K-dim = 10 <= 16)
// in bf16 hi/lo, 3-term product (hi*hi + hi*lo + lo*hi; err ~1e-4 abs).
// D = mfma(A=Xj-side 32x16, B=Xi-side 16x32) -> D[j][i] with verified C/D
// layout col=lane&31 (FIXED i per lane), row j = (reg&3)+8*(reg>>2)+4*(l>>5).
// Then lane-local: K = exp2(nih2*sq); S0 += K; V_d += K*xj_d (xj via
// broadcast loads, one base + immediate offsets per tile).
// Block 512 = 8 waves, all on the same 32-row i-tile, j split 8 ways
// (wave w: j in [w*256, w*256+256)). grid (BATCH, 64) = 512 blocks,
// 2 blocks/CU = 16 waves/CU. LDS: 18.4 KB partial combine only.
//   phi = (1/N) * ( S0*(obs_d - xi_d) + (1 + 2/h)*(S0*xi_d - V_d) )
// first=1: RMSprop state treated as zero (not read).
// ---------------------------------------------------------------------------
__global__ __launch_bounds__(512, 4) void svgd_step_k(const float* __restrict__ x_in,
                                                      float* __restrict__ x_out,
                                                      float* __restrict__ s,
                                                      const float* __restrict__ hpar,
                                                      const float* __restrict__ obs,
                                                      int first) {
    __shared__ float part[32][16][9]; // 18.4 KB: [i-col][wave*2+half][S0|V0..7]

    const int b = blockIdx.x;
    const int tid = threadIdx.x;
    const int w = tid >> 6;      // wave 0..7
    const int l = tid & 63;
    const int col = l & 31;      // this lane's i-column (and frag row index)
    const int half = l >> 5;     // k-half / row-offset select
    const float* xb = x_in + (size_t)b * NPART * DDIM;

    const float nih2 = hpar[2 * b + 0];  // -log2e/h
    const float c2 = hpar[2 * b + 1];    //  2/h
    const int ibase = blockIdx.y * 32;

    // ---- B operand (i-side), built once: [-2xi (k0..7), 1 (k8), qi (k9), 0..]
    FragU Bh, Bl;
    {
        const float* xi = xb + (size_t)(ibase + col) * DDIM;
        const v4f t0 = ((const v4f*)xi)[0];
        const v4f t1 = ((const v4f*)xi)[1];
        const float qi = t0.x * t0.x + t0.y * t0.y + t0.z * t0.z + t0.w * t0.w
                       + t1.x * t1.x + t1.y * t1.y + t1.z * t1.z + t1.w * t1.w;
        if (half == 0) {
            const float e0 = -2.0f * t0.x, e1 = -2.0f * t0.y;
            const float e2 = -2.0f * t0.z, e3 = -2.0f * t0.w;
            const float e4 = -2.0f * t1.x, e5 = -2.0f * t1.y;
            const float e6 = -2.0f * t1.z, e7 = -2.0f * t1.w;
            Bh.u[0] = pk_bf16(e0, e1);
            Bh.u[1] = pk_bf16(e2, e3);
            Bh.u[2] = pk_bf16(e4, e5);
            Bh.u[3] = pk_bf16(e6, e7);
            Bl.u[0] = pk_bf16(e0 - btrunc(e0), e1 - btrunc(e1));
            Bl.u[1] = pk_bf16(e2 - btrunc(e2), e3 - btrunc(e3));
            Bl.u[2] = pk_bf16(e4 - btrunc(e4), e5 - btrunc(e5));
            Bl.u[3] = pk_bf16(e6 - btrunc(e6), e7 - btrunc(e7));
        } else {
            Bh.u[0] = pk_bf16(1.0f, qi);               // k8 = 1, k9 = qi_hi
            Bl.u[0] = pk_bf16(0.0f, qi - btrunc(qi));  //          k9 = qi_lo
            Bh.u[1] = Bh.u[2] = Bh.u[3] = 0u;
            Bl.u[1] = Bl.u[2] = Bl.u[3] = 0u;
        }
    }

    float S0 = 0.0f;
    float V0 = 0, V1 = 0, V2 = 0, V3 = 0, V4 = 0, V5 = 0, V6 = 0, V7 = 0;

    for (int t = 0; t < 8; ++t) {
        const int jbase = w * 256 + t * 32;
        // ---- A operand (j-side): [xj (k0..7), qj (k8), 1 (k9), 0..]
        FragU Ah, Al;
        {
            const float* xj = xb + (size_t)(jbase + col) * DDIM;
            const v4f u0 = ((const v4f*)xj)[0];
            const v4f u1 = ((const v4f*)xj)[1];
            const float qj = u0.x * u0.x + u0.y * u0.y + u0.z * u0.z + u0.w * u0.w
                           + u1.x * u1.x + u1.y * u1.y + u1.z * u1.z + u1.w * u1.w;
            if (half == 0) {
                Ah.u[0] = pk_bf16(u0.x, u0.y);
                Ah.u[1] = pk_bf16(u0.z, u0.w);
                Ah.u[2] = pk_bf16(u1.x, u1.y);
                Ah.u[3] = pk_bf16(u1.z, u1.w);
                Al.u[0] = pk_bf16(u0.x - btrunc(u0.x), u0.y - btrunc(u0.y));
                Al.u[1] = pk_bf16(u0.z - btrunc(u0.z), u0.w - btrunc(u0.w));
                Al.u[2] = pk_bf16(u1.x - btrunc(u1.x), u1.y - btrunc(u1.y));
                Al.u[3] = pk_bf16(u1.z - btrunc(u1.z), u1.w - btrunc(u1.w));
            } else {
                Ah.u[0] = pk_bf16(qj, 1.0f);               // k8 = qj_hi, k9 = 1
                Al.u[0] = pk_bf16(qj - btrunc(qj), 0.0f);  // k8 = qj_lo
                Ah.u[1] = Ah.u[2] = Ah.u[3] = 0u;
                Al.u[1] = Al.u[2] = Al.u[3] = 0u;
            }
        }
        f32x16 acc = {0, 0, 0, 0, 0, 0, 0, 0, 0, 0, 0, 0, 0, 0, 0, 0};
        acc = __builtin_amdgcn_mfma_f32_32x32x16_bf16(Ah.v, Bh.v, acc, 0, 0, 0);
        acc = __builtin_amdgcn_mfma_f32_32x32x16_bf16(Ah.v, Bl.v, acc, 0, 0, 0);
        acc = __builtin_amdgcn_mfma_f32_32x32x16_bf16(Al.v, Bh.v, acc, 0, 0, 0);

        // lane: col i fixed; regs cover 16 j-rows = (reg&3)+8*(reg>>2)+4*half
        const float* xrbase = xb + (size_t)(jbase + 4 * half) * DDIM;
#pragma unroll
        for (int reg = 0; reg < 16; ++reg) {
            const int joff = (reg & 3) + 8 * (reg >> 2); // + 4*half in base
            const float K = __builtin_amdgcn_exp2f(nih2 * acc[reg]);
            const v4f a0 = ((const v4f*)(xrbase + (size_t)joff * DDIM))[0];
            const v4f a1 = ((const v4f*)(xrbase + (size_t)joff * DDIM))[1];
            S0 += K;
            V0 = fmaf(K, a0.x, V0);
            V1 = fmaf(K, a0.y, V1);
            V2 = fmaf(K, a0.z, V2);
            V3 = fmaf(K, a0.w, V3);
            V4 = fmaf(K, a1.x, V4);
            V5 = fmaf(K, a1.y, V5);
            V6 = fmaf(K, a1.z, V6);
            V7 = fmaf(K, a1.w, V7);
        }
    }

    const int pslot = w * 2 + half;
    part[col][pslot][0] = S0;
    part[col][pslot][1] = V0;
    part[col][pslot][2] = V1;
    part[col][pslot][3] = V2;
    part[col][pslot][4] = V3;
    part[col][pslot][5] = V4;
    part[col][pslot][6] = V5;
    part[col][pslot][7] = V6;
    part[col][pslot][8] = V7;
    __syncthreads();

    // phase 2: threads 0..255 = 32 rows x 8 dims; reduce 16 partials
    if (tid < 256) {
        const int d2i = tid & 7;
        const int r2 = tid >> 3;
        const int i2 = ibase + r2;
        float S0t = 0.0f, Vt = 0.0f;
#pragma unroll
        for (int p = 0; p < 16; ++p) {
            S0t += part[r2][p][0];
            Vt += part[r2][p][1 + d2i];
        }
        const size_t idx = ((size_t)b * NPART + i2) * DDIM + d2i;
        const float xid = x_in[idx];
        const float obsd = obs[b * DDIM + d2i];
        const float U = fmaf(S0t, xid, -Vt);       // sum_j K*(xi - xj)
        const float T = fmaf(S0t, obsd - xid, U);  // sum_j K*(obs - xj)
        const float phi = INV_N * fmaf(c2, U, T);
        float sv;
        if (first) {
            sv = (1.0f - ALPHA) * phi * phi;
        } else {
            sv = ALPHA * s[idx] + (1.0f - ALPHA) * phi * phi;
        }
        s[idx] = sv;
        x_out[idx] = xid + LR * phi / (sqrtf(sv) + EPS);
    }
}

// ---------------------------------------------------------------------------
extern "C" void kernel_launch(void* const* d_in, const int* in_sizes, int n_in,
                              void* d_out, int out_size, void* d_ws, size_t ws_size,
                              hipStream_t stream) {
    const float* x0 = (const float*)d_in[0];   // [8,2048,8]
    const float* obs = (const float*)d_in[1];  // [8,8]
    float* out = (float*)d_out;                // [8,2048,8]

    // workspace layout (~1.07 MB)
    float* xa = (float*)d_ws;                          // ping-pong x
    float* s = xa + BATCH * NPART * DDIM;              // RMSprop state
    unsigned* hist = (unsigned*)(s + BATCH * NPART * DDIM);
    unsigned* prefix = hist + BATCH * 2 * 256;
    unsigned* rank = prefix + BATCH * 2;
    float* hpar = (float*)(rank + BATCH * 2);

    init_ws_k<<<16, 256, 0, stream>>>(hist, prefix, rank);

    // median via 3-round SYMMETRIC radix select on float bit patterns
    for (int r = 0; r < 3; ++r) {
        const int shift = 24 - 8 * r;
        median_hist_k<<<dim3(BATCH, 128), 256, 0, stream>>>(x0, hist, prefix, shift);
        median_scan_k<<<1, 64, 0, stream>>>(hist, prefix, rank, shift, hpar);
    }

    // 5 SVGD iterations, ping-ponging between d_out and ws; ends in d_out
    svgd_step_k<<<dim3(BATCH, 64), 512, 0, stream>>>(x0, out, s, hpar, obs, 1);
    svgd_step_k<<<dim3(BATCH, 64), 512, 0, stream>>>(out, xa, s, hpar, obs, 0);
    svgd_step_k<<<dim3(BATCH, 64), 512, 0, stream>>>(xa, out, s, hpar, obs, 0);
    svgd_step_k<<<dim3(BATCH, 64), 512, 0, stream>>>(out, xa, s, hpar, obs, 0);
    svgd_step_k<<<dim3(BATCH, 64), 512, 0, stream>>>(xa, out, s, hpar, obs, 0);
}

// Round 13
// 214.599 us; speedup vs baseline: 1.2739x; 1.2739x over previous
//
#include <hip/hip_runtime.h>
#include <cstdint>

#define BATCH 8
#define NPART 2048
#define DDIM 8
#define NN (NPART * NPART) /* 4194304 ordered pairs per batch */

#define MJCHUNK 128   // median j-tile: 4.6 KB stage + 32 KB hist -> 4 blocks/CU

constexpr float LR = 0.1f;
constexpr float ALPHA = 0.9f;
constexpr float EPS = 1e-8f;
constexpr float INV_N = 1.0f / (float)NPART;
constexpr float LOG2E = 1.44269504088896340736f;

typedef float v2f __attribute__((ext_vector_type(2)));
typedef float v4f __attribute__((ext_vector_type(4)));

// ---------------------------------------------------------------------------
// init: zero radix histograms + select state (RMSprop s is never pre-zeroed:
// the first svgd step computes s = (1-a)*phi^2 directly, not reading s).
// ---------------------------------------------------------------------------
__global__ __launch_bounds__(256) void init_ws_k(unsigned* __restrict__ hist,
                                                 unsigned* __restrict__ prefix,
                                                 unsigned* __restrict__ rank) {
    const int tid = blockIdx.x * 256 + threadIdx.x;
    if (tid < BATCH * 2 * 256) hist[tid] = 0u;
    if (tid < BATCH * 2) {
        prefix[tid] = 0u;
        rank[tid] = (unsigned)(NN / 2) + (unsigned)(tid & 1); // 2097152 / 2097153
    }
}

// ---------------------------------------------------------------------------
// SYMMETRIC radix-select histogram pass (round-11 proven, unchanged).
// ---------------------------------------------------------------------------
__global__ __launch_bounds__(256) void median_hist_k(const float* __restrict__ x,
                                                     unsigned* __restrict__ hist,
                                                     const unsigned* __restrict__ prefix,
                                                     int shift) {
    __shared__ __align__(16) v4f xs0[MJCHUNK]; // xj dims 0-3
    __shared__ __align__(16) v4f xs1[MJCHUNK]; // xj dims 4-7
    __shared__ float rs[MJCHUNK];              // |xj|^2
    __shared__ unsigned lh[256 * 32];          // 32 KB slot-privatized bins

    const int b = blockIdx.x;
    const int tid = threadIdx.x;
    const int lane = tid & 63;   // j-lane
    const int slot = tid & 31;
    const int trow = tid >> 6;   // 0..3
    const float* xb = x + (size_t)b * NPART * DDIM;

    const unsigned p0 = prefix[2 * b + 0];
    const unsigned p1 = prefix[2 * b + 1];
    const bool same = (p0 == p1);
    const unsigned mask = (shift == 24) ? 0u : (0xFFFFFFFFu << (shift + 8));

    const int nsel = same ? 1 : 2;
    for (int sel = 0; sel < nsel; ++sel) {
        const unsigned pref = sel ? p1 : p0;
        __syncthreads();
        for (int t = tid; t < 256 * 32; t += 256) lh[t] = 0u;

        for (int sp = 0; sp < 2; ++sp) {
            const int strip = sp ? (255 - (int)blockIdx.y) : (int)blockIdx.y;
            const int ibase = strip * 8 + trow * 2;
            v2f xi[2][4];
            float q[2];
#pragma unroll
            for (int rr = 0; rr < 2; ++rr) {
                const v4f t0 = ((const v4f*)(xb + (size_t)(ibase + rr) * DDIM))[0];
                const v4f t1 = ((const v4f*)(xb + (size_t)(ibase + rr) * DDIM))[1];
                xi[rr][0] = t0.xy; xi[rr][1] = t0.zw;
                xi[rr][2] = t1.xy; xi[rr][3] = t1.zw;
                q[rr] = t0.x * t0.x + t0.y * t0.y + t0.z * t0.z + t0.w * t0.w
                      + t1.x * t1.x + t1.y * t1.y + t1.z * t1.z + t1.w * t1.w;
            }
            const int c0 = (strip >> 4) * MJCHUNK; // first chunk touching strip
            for (int cbase = c0; cbase < NPART; cbase += MJCHUNK) {
                __syncthreads();
                for (int t = tid; t < MJCHUNK; t += 256) {
                    const v4f u0 = ((const v4f*)(xb + (size_t)(cbase + t) * DDIM))[0];
                    const v4f u1 = ((const v4f*)(xb + (size_t)(cbase + t) * DDIM))[1];
                    xs0[t] = u0;
                    xs1[t] = u1;
                    rs[t] = u0.x * u0.x + u0.y * u0.y + u0.z * u0.z + u0.w * u0.w
                          + u1.x * u1.x + u1.y * u1.y + u1.z * u1.z + u1.w * u1.w;
                }
                __syncthreads();
#pragma unroll
                for (int j = lane; j < MJCHUNK; j += 64) {
                    const int jg = cbase + j;
                    const v4f A = xs0[j];
                    const v4f B = xs1[j];
                    const float r = rs[j];
                    const v2f A0 = A.xy, A1 = A.zw, B0 = B.xy, B1 = B.zw;
#pragma unroll
                    for (int rr = 0; rr < 2; ++rr) {
                        v2f p = A0 * xi[rr][0];
                        p += A1 * xi[rr][1];
                        p += B0 * xi[rr][2];
                        p += B1 * xi[rr][3];
                        const float sq = fmaxf(fmaf(-2.0f, p.x + p.y, q[rr] + r), 0.0f);
                        const unsigned u = __float_as_uint(sq);
                        if (jg > ibase + rr && (u & mask) == pref)
                            atomicAdd(&lh[((u >> shift) & 255u) * 32 + slot], 2u);
                    }
                }
            }
        }
        __syncthreads();
        unsigned tot = 0;
#pragma unroll
        for (int sct = 0; sct < 32; ++sct) tot += lh[tid * 32 + ((sct + tid) & 31)];
        if (tot) {
            atomicAdd(&hist[b * 512 + sel * 256 + tid], tot);
            if (same) atomicAdd(&hist[b * 512 + 256 + tid], tot);
        }
    }
}

// ---------------------------------------------------------------------------
// scan (round-11 proven, unchanged): diagonal zeros added analytically.
// Final round (shift==8): hpar = { -log2e/h, 2/h }.
// ---------------------------------------------------------------------------
__global__ void median_scan_k(unsigned* __restrict__ hist,
                              unsigned* __restrict__ prefix,
                              unsigned* __restrict__ rank,
                              int shift,
                              float* __restrict__ hpar) {
    __shared__ unsigned selv[16];
    const int t = threadIdx.x;
    if (t < 16) {
        const unsigned r = rank[t];
        const unsigned pref = prefix[t];
        const unsigned* hb = hist + t * 256;
        unsigned cum = 0;
        int bin = 0;
        for (; bin < 256; ++bin) {
            unsigned c = hb[bin];
            if (bin == 0 && pref == 0u) c += (unsigned)NPART; // diagonal zeros
            if (cum + c >= r) break;
            cum += c;
        }
        if (bin > 255) bin = 255;
        const unsigned np = pref | ((unsigned)bin << shift);
        prefix[t] = np;
        rank[t] = r - cum;
        selv[t] = np;
    }
    __syncthreads();
    for (int q = t; q < 16 * 256; q += 64) hist[q] = 0u;
    if (shift == 8 && t < BATCH) {
        const float v1 = __uint_as_float(selv[2 * t + 0]);
        const float v2 = __uint_as_float(selv[2 * t + 1]);
        const float med = 0.5f * (sqrtf(v1) + sqrtf(v2));
        const float h = (med * med) / logf((float)NPART);
        hpar[2 * t + 0] = -LOG2E / h;
        hpar[2 * t + 1] = 2.0f / h;
    }
}

// ---------------------------------------------------------------------------
// rs seed for the first svgd step: rs[row] = nih2_b * |x0_row|^2.
// Must run AFTER the median (needs hpar). 16384 rows.
// ---------------------------------------------------------------------------
__global__ __launch_bounds__(256) void rs0_k(const float* __restrict__ x,
                                             const float* __restrict__ hpar,
                                             float* __restrict__ rs) {
    const int row = blockIdx.x * 256 + threadIdx.x;
    if (row < BATCH * NPART) {
        const int b = row >> 11;
        const float nih2 = hpar[2 * b + 0];
        const v4f t0 = ((const v4f*)(x + (size_t)row * DDIM))[0];
        const v4f t1 = ((const v4f*)(x + (size_t)row * DDIM))[1];
        rs[row] = nih2 * (t0.x * t0.x + t0.y * t0.y + t0.z * t0.z + t0.w * t0.w
                        + t1.x * t1.x + t1.y * t1.y + t1.z * t1.z + t1.w * t1.w);
    }
}

// ---------------------------------------------------------------------------
// one SVGD + RMSprop step, dot-expansion in exp2 domain — BARRIER-FREE main
// loop: xj and rs_j read directly from global (L2-resident; coalesced 32 B/lane
// stride). rs = nih2*|x|^2 is carried in a ping-ponged global array written by
// the PREVIOUS step's epilogue (identical fp32 ops -> bitwise-identical phi
// vs the LDS-staged version).
//   K = exp2(cdot2*<xi,xj> + q + rs_j), q = nih2*|xi|^2
//   S0 = sum_j K;  V_d = sum_j K*xj_d;  U_d = S0*xi_d - V_d
//   phi = (1/N) * ( S0*(obs_d - xi_d) + (1 + 2/h)*U_d )
// block 256 = 64 j-lanes x 4 trows x 4 rows = 16 rows; grid (BATCH, 128).
// Epilogue also writes rs_out from the new x (8-lane shfl row reduction).
// first=1: RMSprop state treated as zero (not read).
// ---------------------------------------------------------------------------
__global__ __launch_bounds__(256, 4) void svgd_step_k(const float* __restrict__ x_in,
                                                      float* __restrict__ x_out,
                                                      float* __restrict__ s,
                                                      const float* __restrict__ hpar,
                                                      const float* __restrict__ obs,
                                                      const float* __restrict__ rs_in,
                                                      float* __restrict__ rs_out,
                                                      int first) {
    __shared__ float part[16][8][9]; // 4.6 KB partial combine

    const int b = blockIdx.x;
    const int tid = threadIdx.x;
    const int lane = tid & 63;  // j-lane
    const int trow = tid >> 6;  // 0..3
    const float* xb = x_in + (size_t)b * NPART * DDIM;
    const float* rb = rs_in + (size_t)b * NPART;

    const float nih2 = hpar[2 * b + 0];  // -log2e/h
    const float c2 = hpar[2 * b + 1];    //  2/h
    const float cdot2 = -2.0f * nih2;

    const int ibase = blockIdx.y * 16 + trow * 4;
    v2f xi[4][4];
    float q[4];
#pragma unroll
    for (int rr = 0; rr < 4; ++rr) {
        const v4f t0 = ((const v4f*)(xb + (size_t)(ibase + rr) * DDIM))[0];
        const v4f t1 = ((const v4f*)(xb + (size_t)(ibase + rr) * DDIM))[1];
        xi[rr][0] = t0.xy; xi[rr][1] = t0.zw;
        xi[rr][2] = t1.xy; xi[rr][3] = t1.zw;
        q[rr] = nih2 * (t0.x * t0.x + t0.y * t0.y + t0.z * t0.z + t0.w * t0.w
                      + t1.x * t1.x + t1.y * t1.y + t1.z * t1.z + t1.w * t1.w);
    }

    float S0[4] = {0, 0, 0, 0};
    v2f V[4][4];
#pragma unroll
    for (int rr = 0; rr < 4; ++rr)
#pragma unroll
        for (int k = 0; k < 4; ++k) V[rr][k] = (v2f){0, 0};

#pragma unroll 4
    for (int j = lane; j < NPART; j += 64) {
        const v4f A = ((const v4f*)(xb + (size_t)j * DDIM))[0];
        const v4f B = ((const v4f*)(xb + (size_t)j * DDIM))[1];
        const float r = rb[j];
        const v2f A0 = A.xy, A1 = A.zw, B0 = B.xy, B1 = B.zw;
#pragma unroll
        for (int rr = 0; rr < 4; ++rr) {
            v2f p = A0 * xi[rr][0];
            p += A1 * xi[rr][1];
            p += B0 * xi[rr][2];
            p += B1 * xi[rr][3];
            const float K = __builtin_amdgcn_exp2f(fmaf(cdot2, p.x + p.y, q[rr] + r));
            S0[rr] += K;
            const v2f K2 = {K, K};
            V[rr][0] += A0 * K2;
            V[rr][1] += A1 * K2;
            V[rr][2] += B0 * K2;
            V[rr][3] += B1 * K2;
        }
    }

    // in-register lane pre-reduce (64 -> 8 partial lanes), then LDS combine
#pragma unroll
    for (int rr = 0; rr < 4; ++rr) {
        float t0 = S0[rr];
        float t1 = V[rr][0].x, t2 = V[rr][0].y;
        float t3 = V[rr][1].x, t4 = V[rr][1].y;
        float t5 = V[rr][2].x, t6 = V[rr][2].y;
        float t7 = V[rr][3].x, t8 = V[rr][3].y;
        t0 += __shfl_xor(t0, 32); t0 += __shfl_xor(t0, 16); t0 += __shfl_xor(t0, 8);
        t1 += __shfl_xor(t1, 32); t1 += __shfl_xor(t1, 16); t1 += __shfl_xor(t1, 8);
        t2 += __shfl_xor(t2, 32); t2 += __shfl_xor(t2, 16); t2 += __shfl_xor(t2, 8);
        t3 += __shfl_xor(t3, 32); t3 += __shfl_xor(t3, 16); t3 += __shfl_xor(t3, 8);
        t4 += __shfl_xor(t4, 32); t4 += __shfl_xor(t4, 16); t4 += __shfl_xor(t4, 8);
        t5 += __shfl_xor(t5, 32); t5 += __shfl_xor(t5, 16); t5 += __shfl_xor(t5, 8);
        t6 += __shfl_xor(t6, 32); t6 += __shfl_xor(t6, 16); t6 += __shfl_xor(t6, 8);
        t7 += __shfl_xor(t7, 32); t7 += __shfl_xor(t7, 16); t7 += __shfl_xor(t7, 8);
        t8 += __shfl_xor(t8, 32); t8 += __shfl_xor(t8, 16); t8 += __shfl_xor(t8, 8);
        if (lane < 8) {
            const int row = trow * 4 + rr;
            part[row][lane][0] = t0;
            part[row][lane][1] = t1;
            part[row][lane][2] = t2;
            part[row][lane][3] = t3;
            part[row][lane][4] = t4;
            part[row][lane][5] = t5;
            part[row][lane][6] = t6;
            part[row][lane][7] = t7;
            part[row][lane][8] = t8;
        }
    }
    __syncthreads();

    // phase 2: threads 0..127 = 16 rows x 8 dims; reduce 8 lane-partials
    if (tid < 128) {
        const int d2i = tid & 7;
        const int r2 = tid >> 3;
        const int i2 = blockIdx.y * 16 + r2;
        float S0t = 0.0f, Vt = 0.0f;
#pragma unroll
        for (int l = 0; l < 8; ++l) {
            S0t += part[r2][l][0];
            Vt += part[r2][l][1 + d2i];
        }
        const size_t idx = ((size_t)b * NPART + i2) * DDIM + d2i;
        const float xid = x_in[idx];
        const float obsd = obs[b * DDIM + d2i];
        const float U = fmaf(S0t, xid, -Vt);       // sum_j K*(xi - xj)
        const float T = fmaf(S0t, obsd - xid, U);  // sum_j K*(obs - xj)
        const float phi = INV_N * fmaf(c2, U, T);
        float sv;
        if (first) {
            sv = (1.0f - ALPHA) * phi * phi;
        } else {
            sv = ALPHA * s[idx] + (1.0f - ALPHA) * phi * phi;
        }
        s[idx] = sv;
        const float xn = xid + LR * phi / (sqrtf(sv) + EPS);
        x_out[idx] = xn;
        // rs for the NEXT step: row-sum of xn^2 over the 8 dims (8-lane group)
        float sq = xn * xn;
        sq += __shfl_xor(sq, 1);
        sq += __shfl_xor(sq, 2);
        sq += __shfl_xor(sq, 4);
        if (d2i == 0) rs_out[(size_t)b * NPART + i2] = nih2 * sq;
    }
}

// ---------------------------------------------------------------------------
extern "C" void kernel_launch(void* const* d_in, const int* in_sizes, int n_in,
                              void* d_out, int out_size, void* d_ws, size_t ws_size,
                              hipStream_t stream) {
    const float* x0 = (const float*)d_in[0];   // [8,2048,8]
    const float* obs = (const float*)d_in[1];  // [8,8]
    float* out = (float*)d_out;                // [8,2048,8]

    // workspace layout (~1.2 MB)
    float* xa = (float*)d_ws;                          // ping-pong x
    float* s = xa + BATCH * NPART * DDIM;              // RMSprop state
    unsigned* hist = (unsigned*)(s + BATCH * NPART * DDIM);
    unsigned* prefix = hist + BATCH * 2 * 256;
    unsigned* rank = prefix + BATCH * 2;
    float* hpar = (float*)(rank + BATCH * 2);
    float* rsA = hpar + BATCH * 2;                     // 64 KB
    float* rsB = rsA + BATCH * NPART;                  // 64 KB

    init_ws_k<<<16, 256, 0, stream>>>(hist, prefix, rank);

    // median via 3-round SYMMETRIC radix select on float bit patterns
    for (int r = 0; r < 3; ++r) {
        const int shift = 24 - 8 * r;
        median_hist_k<<<dim3(BATCH, 128), 256, 0, stream>>>(x0, hist, prefix, shift);
        median_scan_k<<<1, 64, 0, stream>>>(hist, prefix, rank, shift, hpar);
    }

    // seed rs from x0 (needs hpar -> after median)
    rs0_k<<<64, 256, 0, stream>>>(x0, hpar, rsA);

    // 5 SVGD iterations, ping-ponging x between d_out and ws and rs A<->B
    svgd_step_k<<<dim3(BATCH, 128), 256, 0, stream>>>(x0, out, s, hpar, obs, rsA, rsB, 1);
    svgd_step_k<<<dim3(BATCH, 128), 256, 0, stream>>>(out, xa, s, hpar, obs, rsB, rsA, 0);
    svgd_step_k<<<dim3(BATCH, 128), 256, 0, stream>>>(xa, out, s, hpar, obs, rsA, rsB, 0);
    svgd_step_k<<<dim3(BATCH, 128), 256, 0, stream>>>(out, xa, s, hpar, obs, rsB, rsA, 0);
    svgd_step_k<<<dim3(BATCH, 128), 256, 0, stream>>>(xa, out, s, hpar, obs, rsA, rsB, 0);
}